// Round 5
// baseline (179.661 us; speedup 1.0000x reference)
//
#include <hip/hip_runtime.h>
#include <hip/hip_bf16.h>

typedef unsigned short u16;
typedef unsigned int u32;
typedef __attribute__((ext_vector_type(8))) short bf16x8;
typedef __attribute__((ext_vector_type(4))) float f32x4;
typedef __attribute__((ext_vector_type(4))) u16 u16x4;

#define B_ 8
#define C_ 512
#define N_ 4096
#define KD_ 64
#define VD_ 512
#define OD_ 512

static __device__ __forceinline__ float bf2f(u16 u) {
    union { u32 i; float f; } z; z.i = ((u32)u) << 16; return z.f;
}
static __device__ __forceinline__ u16 f2bf(float f) {
    union { float f; u32 u; } v; v.f = f;
    u32 r = v.u + 0x7fffu + ((v.u >> 16) & 1u);
    return (u16)(r >> 16);
}
// chunk-rotation swizzle: logical chunk c of row r sits at position (c+swz(r))&3
static __device__ __forceinline__ int swz(int row) { return ((row >> 2) + (row >> 4)) & 3; }

// raw barrier: lgkm drain (my ds ops done) -> s_barrier. Global loads stay
// IN FLIGHT across it (no vmcnt(0) drain, unlike __syncthreads()).
static __device__ __forceinline__ void tile_barrier() {
    asm volatile("s_waitcnt lgkmcnt(0)" ::: "memory");
    __builtin_amdgcn_s_barrier();
    asm volatile("" ::: "memory");
}

// ---------------------------------------------------------------------------
// Blocks >= 1024: Wf f32->bf16 (always). Blocks 0..1023: x -> xT transpose
// (bf16, pixel-major [B][N][C]) — now ALWAYS needed: the gemm streams its
// A-fragments straight from xT. Regridded 256->1024 blocks (4 iters) for TLP.
// ---------------------------------------------------------------------------
__global__ __launch_bounds__(256) void transpose_convert_kernel(
    const float* __restrict__ x, const float* __restrict__ Wf,
    u16* __restrict__ xT, u16* __restrict__ Wf16)
{
    const int t = threadIdx.x;
    if (blockIdx.x >= 1024) {
        const int tid = (blockIdx.x - 1024) * 256 + t;
        const float4* src = (const float4*)Wf + (size_t)tid * 16;
        u16* dst = Wf16 + (size_t)tid * 64;
        #pragma unroll
        for (int j = 0; j < 16; j++) {
            const float4 f = src[j];
            u16x4 p;
            p[0] = f2bf(f.x); p[1] = f2bf(f.y); p[2] = f2bf(f.z); p[3] = f2bf(f.w);
            *(u16x4*)(dst + j * 4) = p;
        }
        return;
    }
    __shared__ u32 tile[64][33];
    for (int it = 0; it < 4; it++) {
        const int bid = it * 1024 + blockIdx.x;
        const int nt = bid & 63;
        const int ct = (bid >> 6) & 7;
        const int b  = bid >> 9;
        const float* xb  = x  + ((size_t)b * C_ + ct * 64) * N_ + nt * 64;
        u16*         xTb = xT + ((size_t)b * N_ + nt * 64) * C_ + ct * 64;
        {
            const int p  = t >> 3;
            const int n8 = t & 7;
            const float* r0 = xb + (size_t)(2 * p)     * N_ + n8 * 8;
            const float* r1 = xb + (size_t)(2 * p + 1) * N_ + n8 * 8;
            const float4 a0 = *(const float4*)(r0);
            const float4 a1 = *(const float4*)(r0 + 4);
            const float4 c0 = *(const float4*)(r1);
            const float4 c1 = *(const float4*)(r1 + 4);
            const float av[8] = { a0.x, a0.y, a0.z, a0.w, a1.x, a1.y, a1.z, a1.w };
            const float cv[8] = { c0.x, c0.y, c0.z, c0.w, c1.x, c1.y, c1.z, c1.w };
            #pragma unroll
            for (int j = 0; j < 8; j++)
                tile[n8 * 8 + j][p] = (u32)f2bf(av[j]) | ((u32)f2bf(cv[j]) << 16);
        }
        __syncthreads();
        #pragma unroll
        for (int h = 0; h < 2; h++) {
            const int id = t + h * 256;
            const int n  = id >> 3;
            const int q  = id & 7;
            uint4 val;
            val.x = tile[n][q * 4 + 0];
            val.y = tile[n][q * 4 + 1];
            val.z = tile[n][q * 4 + 2];
            val.w = tile[n][q * 4 + 3];
            *(uint4*)(xTb + (size_t)n * C_ + q * 8) = val;
        }
        __syncthreads();              // tile reuse across it-loop
    }
}

// ---------------------------------------------------------------------------
// GENERAL PATH (device-gated on gamma != 0; exact no-op when gamma == 0).
// ---------------------------------------------------------------------------
__global__ __launch_bounds__(256) void proj_kernel(
    const u16* __restrict__ xT,
    const float* __restrict__ Wq, const float* __restrict__ bq,
    const float* __restrict__ Wk, const float* __restrict__ bk,
    const float* __restrict__ Wv, const float* __restrict__ bv,
    const float* __restrict__ gamma,
    u16* __restrict__ q, u16* __restrict__ k, u16* __restrict__ v)
{
    if (gamma[0] == 0.0f) return;
    for (int it = 0; it < 2; it++) {
        const int bid = it * 256 + blockIdx.x;
        const int b = bid >> 6;
        const int p = (bid & 63) * 64 + (threadIdx.x & 63);
        const int dg = threadIdx.x >> 6;
        const u16* xrow = xT + ((size_t)b * N_ + p) * C_;
        for (int d0 = dg * 160; d0 < dg * 160 + 160; d0++) {
            const float* wrow; float bias; u16* dst; int dd; int dim;
            if (d0 < 64)       { dd = d0;       wrow = Wq + (size_t)dd * C_; bias = bq[dd]; dst = q; dim = KD_; }
            else if (d0 < 128) { dd = d0 - 64;  wrow = Wk + (size_t)dd * C_; bias = bk[dd]; dst = k; dim = KD_; }
            else               { dd = d0 - 128; wrow = Wv + (size_t)dd * C_; bias = bv[dd]; dst = v; dim = VD_; }
            float s = bias;
            for (int c = 0; c < C_; c++) s += bf2f(xrow[c]) * wrow[c];
            dst[((size_t)b * dim + dd) * N_ + p] = f2bf(s);
        }
    }
}

__global__ __launch_bounds__(256) void attn_kernel(
    const u16* __restrict__ xT, const u16* __restrict__ q,
    const u16* __restrict__ k, const u16* __restrict__ v,
    const float* __restrict__ gamma, u16* __restrict__ yT)
{
    const float g = gamma[0];
    if (g == 0.0f) return;
    __shared__ float pls[4][64];
    const int wv = threadIdx.x >> 6, lane = threadIdx.x & 63;
    for (int it = 0; it < 4; it++) {
        const int bid = it * 256 + blockIdx.x;
        const int b  = bid >> 7;
        const int q0 = (bid & 127) * 32 + wv * 8;
        const u16* kb = k + (size_t)b * KD_ * N_;
        const u16* vb = v + (size_t)b * VD_ * N_;
        for (int qi = 0; qi < 8; qi++) {
            const int i = q0 + qi;
            const float qv = bf2f(q[((size_t)b * KD_ + lane) * N_ + i]);
            float mx = -1e30f, l = 0.f;
            for (int jb = 0; jb < N_; jb += 64) {
                float e = 0.f;
                for (int kd = 0; kd < 64; kd++)
                    e += __shfl(qv, kd) * bf2f(kb[(size_t)kd * N_ + jb + lane]);
                const float nm = fmaxf(mx, e);
                l = l * __expf(mx - nm) + __expf(e - nm);
                mx = nm;
            }
            for (int off = 32; off; off >>= 1) {
                const float mo = __shfl_xor(mx, off);
                const float lo = __shfl_xor(l, off);
                const float nm = fmaxf(mx, mo);
                l = l * __expf(mx - nm) + lo * __expf(mo - nm);
                mx = nm;
            }
            float oacc[8];
            #pragma unroll
            for (int r = 0; r < 8; r++) oacc[r] = 0.f;
            for (int jb = 0; jb < N_; jb += 64) {
                float e = 0.f;
                for (int kd = 0; kd < 64; kd++)
                    e += __shfl(qv, kd) * bf2f(kb[(size_t)kd * N_ + jb + lane]);
                __syncthreads();
                pls[wv][lane] = __expf(e - mx);
                __syncthreads();
                for (int jj = 0; jj < 64; jj++) {
                    const float p = pls[wv][jj];
                    #pragma unroll
                    for (int r = 0; r < 8; r++)
                        oacc[r] += p * bf2f(vb[(size_t)(r * 64 + lane) * N_ + jb + jj]);
                }
            }
            const float inv = 1.f / l;
            #pragma unroll
            for (int r = 0; r < 8; r++) {
                const size_t idx = ((size_t)b * N_ + i) * C_ + r * 64 + lane;
                yT[idx] = f2bf(g * oacc[r] * inv + bf2f(xT[idx]));
            }
        }
    }
}

// ---------------------------------------------------------------------------
// Fused GEMM: Out[b][o][n] = ReLU(BN(sum_c Wf[o][c] * A[b][n][c])),
// A = xT (gamma==0) or yT (gamma!=0) — both bf16 pixel-major [B][N][C].
// Round-5 restructure (diagnosis: 2-phase stage/barrier loop is the floor;
// no pipe >40% busy):
//  - W LDS-RESIDENT: 64KB slab = 8 K-tiles of [128o][32c] (chunk-rotation
//    swizzled, proven maps). Staged twice (half 0, half 1) per block.
//  - A-fragments streamed GLOBAL -> REG: one b128 load per frag (lane's
//    8 bf16 are consecutive in C). NO x-LDS, NO packing VALU, and the
//    K-loop has ZERO barriers (3 barriers per block total).
//  - 4-set rotating A-prefetch (compile-time indices), 4 steps deep.
//  - 2 blocks/CU resident (64KB LDS), 8 waves for latency hiding.
// ---------------------------------------------------------------------------
__global__ __launch_bounds__(256, 2) void gemm_bn_relu(
    const u16* __restrict__ xT, const u16* __restrict__ yT,
    const u16* __restrict__ Wf16, const float* __restrict__ gamma,
    const float* __restrict__ bnw, const float* __restrict__ bnb,
    const float* __restrict__ bnm, const float* __restrict__ bnv,
    float* __restrict__ out)
{
    __shared__ u16 lds_w[8 * 128 * 32];   // 64 KB: 8 K-tiles x [128o][32c]

    const int bid = blockIdx.x;
    const int pt8 = bid & 7;
    const int ot  = (bid >> 3) & 3;
    const int g   = bid >> 5;
    const int pt  = (g & 3) * 8 + pt8;
    const int b   = g >> 2;

    const int t = threadIdx.x;
    const int lane = t & 63;
    const int wv = t >> 6;
    const int wm = wv >> 1;
    const int wn = wv & 1;
    const int lcol = lane & 15;
    const int kq = lane >> 4;

    // W staging map (proven: 2-way max, free)
    const int rw = t >> 2, posw = t & 3;
    const int ql = (posw - swz(rw)) & 3;          // logical chunk to load
    const u16* WT0 = Wf16 + (size_t)(ot * 128 + rw) * C_ + ql * 8;
    const u16* WT1 = WT0 + (size_t)64 * C_;
    const int wla0 = rw * 32 + posw * 8;          // u16 LDS offsets
    const int wla1 = wla0 + 64 * 32;

    // B-frag read addresses within one 8KB tile (u16 units), step-invariant
    int baddr[4];
    #pragma unroll
    for (int i = 0; i < 4; i++) {
        const int R = wn * 64 + i * 16 + lcol;
        baddr[i] = R * 32 + ((kq + swz(R)) & 3) * 8;
    }

    // A-frag global bases: lane reads 8 consecutive bf16 along C
    const u16* Asrc = (gamma[0] == 0.0f) ? xT : yT;
    const u16* Ab[4];
    #pragma unroll
    for (int mi = 0; mi < 4; mi++)
        Ab[mi] = Asrc + ((size_t)b * N_ + pt * 128 + wm * 64 + mi * 16 + lcol) * C_ + kq * 8;

    f32x4 acc[4][4];
    #pragma unroll
    for (int i = 0; i < 4; i++)
        #pragma unroll
        for (int j = 0; j < 4; j++)
            acc[i][j] = (f32x4){0.f, 0.f, 0.f, 0.f};

    auto loadA = [&](bf16x8 (&d)[4], int ks) {
        #pragma unroll
        for (int mi = 0; mi < 4; mi++)
            d[mi] = *(const bf16x8*)(Ab[mi] + ks * 32);
    };
    auto stepf = [&](bf16x8 (&af)[4], int ks) {
        const int kt = ks & 7;
        bf16x8 bfg[4];
        #pragma unroll
        for (int ni = 0; ni < 4; ni++)
            bfg[ni] = *(const bf16x8*)&lds_w[kt * 4096 + baddr[ni]];
        #pragma unroll
        for (int mi = 0; mi < 4; mi++)
            #pragma unroll
            for (int ni = 0; ni < 4; ni++)
                acc[mi][ni] = __builtin_amdgcn_mfma_f32_16x16x32_bf16(
                    af[mi], bfg[ni], acc[mi][ni], 0, 0, 0);
    };
    auto stageW = [&](int half) {
        #pragma unroll
        for (int kt = 0; kt < 8; kt++) {
            const uint4 w0 = *(const uint4*)(WT0 + (half * 8 + kt) * 32);
            const uint4 w1 = *(const uint4*)(WT1 + (half * 8 + kt) * 32);
            *(uint4*)&lds_w[kt * 4096 + wla0] = w0;
            *(uint4*)&lds_w[kt * 4096 + wla1] = w1;
        }
    };

    bf16x8 s0[4], s1[4], s2[4], s3[4];
    loadA(s0, 0); loadA(s1, 1); loadA(s2, 2); loadA(s3, 3);   // in flight over W staging
    stageW(0);
    tile_barrier();                 // W half 0 visible; A-loads stay in flight
    stepf(s0, 0);  loadA(s0, 4);
    stepf(s1, 1);  loadA(s1, 5);
    stepf(s2, 2);  loadA(s2, 6);
    stepf(s3, 3);  loadA(s3, 7);
    stepf(s0, 4);  loadA(s0, 8);
    stepf(s1, 5);  loadA(s1, 9);
    stepf(s2, 6);  loadA(s2, 10);
    stepf(s3, 7);  loadA(s3, 11);
    tile_barrier();                 // everyone done reading half 0
    stageW(1);
    tile_barrier();                 // W half 1 visible
    stepf(s0, 8);  loadA(s0, 12);
    stepf(s1, 9);  loadA(s1, 13);
    stepf(s2, 10); loadA(s2, 14);
    stepf(s3, 11); loadA(s3, 15);
    stepf(s0, 12);
    stepf(s1, 13);
    stepf(s2, 14);
    stepf(s3, 15);

    float scale[4], shift[4];
    #pragma unroll
    for (int ni = 0; ni < 4; ni++) {
        const int o = ot * 128 + wn * 64 + ni * 16 + lcol;
        const float s = bnw[o] * rsqrtf(bnv[o] + 1e-5f);
        scale[ni] = s;
        shift[ni] = bnb[o] - bnm[o] * s;
    }
    #pragma unroll
    for (int mi = 0; mi < 4; mi++) {
        const int npix = pt * 128 + wm * 64 + mi * 16 + kq * 4;
        #pragma unroll
        for (int ni = 0; ni < 4; ni++) {
            const int o = ot * 128 + wn * 64 + ni * 16 + lcol;
            f32x4 pk;
            #pragma unroll
            for (int r = 0; r < 4; r++)
                pk[r] = fmaxf(acc[mi][ni][r] * scale[ni] + shift[ni], 0.0f);
            *(f32x4*)(out + ((size_t)b * OD_ + o) * N_ + npix) = pk;
        }
    }
}

extern "C" void kernel_launch(void* const* d_in, const int* in_sizes, int n_in,
                              void* d_out, int out_size, void* d_ws, size_t ws_size,
                              hipStream_t stream) {
    const float* x     = (const float*)d_in[0];
    const float* Wq    = (const float*)d_in[1];
    const float* bq    = (const float*)d_in[2];
    const float* Wk    = (const float*)d_in[3];
    const float* bk    = (const float*)d_in[4];
    const float* Wv    = (const float*)d_in[5];
    const float* bv    = (const float*)d_in[6];
    const float* gamma = (const float*)d_in[7];
    const float* Wf    = (const float*)d_in[8];
    const float* bnw   = (const float*)d_in[9];
    const float* bnb   = (const float*)d_in[10];
    const float* bnm   = (const float*)d_in[11];
    const float* bnv   = (const float*)d_in[12];
    float* out = (float*)d_out;

    char* ws = (char*)d_ws;
    u16* Wf16 = (u16*)(ws);                  //     524,288 B (always)
    u16* xT   = (u16*)(ws + 524288);         // 33,554,432 B (always: gemm A-source)
    u16* yT   = (u16*)(ws + 34078720);       // 33,554,432 B (gated)
    u16* q    = (u16*)(ws + 67633152);       //  4,194,304 B (gated)
    u16* k    = (u16*)(ws + 71827456);       //  4,194,304 B (gated)
    u16* v    = (u16*)(ws + 76021760);       // 33,554,432 B (gated)

    transpose_convert_kernel<<<1040, 256, 0, stream>>>(x, Wf, xT, Wf16);
    proj_kernel<<<256, 256, 0, stream>>>(xT, Wq, bq, Wk, bk, Wv, bv, gamma, q, k, v);
    attn_kernel<<<256, 256, 0, stream>>>(xT, q, k, v, gamma, yT);
    gemm_bn_relu<<<1024, 256, 0, stream>>>(xT, yT, Wf16, gamma, bnw, bnb, bnm, bnv, out);
}

// Round 6
// 179.658 us; speedup vs baseline: 1.0000x; 1.0000x over previous
//
#include <hip/hip_runtime.h>
#include <hip/hip_bf16.h>

typedef unsigned short u16;
typedef unsigned int u32;
typedef __attribute__((ext_vector_type(8))) short bf16x8;
typedef __attribute__((ext_vector_type(4))) float f32x4;
typedef __attribute__((ext_vector_type(4))) u16 u16x4;

#define B_ 8
#define C_ 512
#define N_ 4096
#define KD_ 64
#define VD_ 512
#define OD_ 512

static __device__ __forceinline__ float bf2f(u16 u) {
    union { u32 i; float f; } z; z.i = ((u32)u) << 16; return z.f;
}
static __device__ __forceinline__ u16 f2bf(float f) {
    union { float f; u32 u; } v; v.f = f;
    u32 r = v.u + 0x7fffu + ((v.u >> 16) & 1u);
    return (u16)(r >> 16);
}
// chunk-rotation swizzle: logical chunk c of row r sits at position (c+swz(r))&3
static __device__ __forceinline__ int swz(int row) { return ((row >> 2) + (row >> 4)) & 3; }

// raw barrier: lgkm drain (my ds ops done) -> s_barrier. Global loads stay
// IN FLIGHT across it (no vmcnt(0) drain, unlike __syncthreads()).
static __device__ __forceinline__ void tile_barrier() {
    asm volatile("s_waitcnt lgkmcnt(0)" ::: "memory");
    __builtin_amdgcn_s_barrier();
    asm volatile("" ::: "memory");
}

// ---------------------------------------------------------------------------
// Blocks >= 1024: Wf f32->bf16 (always). Blocks 0..1023: x -> xT transpose
// (bf16, pixel-major [B][N][C]) — always needed: gemm streams A from xT.
// ---------------------------------------------------------------------------
__global__ __launch_bounds__(256) void transpose_convert_kernel(
    const float* __restrict__ x, const float* __restrict__ Wf,
    u16* __restrict__ xT, u16* __restrict__ Wf16)
{
    const int t = threadIdx.x;
    if (blockIdx.x >= 1024) {
        const int tid = (blockIdx.x - 1024) * 256 + t;
        const float4* src = (const float4*)Wf + (size_t)tid * 16;
        u16* dst = Wf16 + (size_t)tid * 64;
        #pragma unroll
        for (int j = 0; j < 16; j++) {
            const float4 f = src[j];
            u16x4 p;
            p[0] = f2bf(f.x); p[1] = f2bf(f.y); p[2] = f2bf(f.z); p[3] = f2bf(f.w);
            *(u16x4*)(dst + j * 4) = p;
        }
        return;
    }
    __shared__ u32 tile[64][33];
    for (int it = 0; it < 4; it++) {
        const int bid = it * 1024 + blockIdx.x;
        const int nt = bid & 63;
        const int ct = (bid >> 6) & 7;
        const int b  = bid >> 9;
        const float* xb  = x  + ((size_t)b * C_ + ct * 64) * N_ + nt * 64;
        u16*         xTb = xT + ((size_t)b * N_ + nt * 64) * C_ + ct * 64;
        {
            const int p  = t >> 3;
            const int n8 = t & 7;
            const float* r0 = xb + (size_t)(2 * p)     * N_ + n8 * 8;
            const float* r1 = xb + (size_t)(2 * p + 1) * N_ + n8 * 8;
            const float4 a0 = *(const float4*)(r0);
            const float4 a1 = *(const float4*)(r0 + 4);
            const float4 c0 = *(const float4*)(r1);
            const float4 c1 = *(const float4*)(r1 + 4);
            const float av[8] = { a0.x, a0.y, a0.z, a0.w, a1.x, a1.y, a1.z, a1.w };
            const float cv[8] = { c0.x, c0.y, c0.z, c0.w, c1.x, c1.y, c1.z, c1.w };
            #pragma unroll
            for (int j = 0; j < 8; j++)
                tile[n8 * 8 + j][p] = (u32)f2bf(av[j]) | ((u32)f2bf(cv[j]) << 16);
        }
        __syncthreads();
        #pragma unroll
        for (int h = 0; h < 2; h++) {
            const int id = t + h * 256;
            const int n  = id >> 3;
            const int q  = id & 7;
            uint4 val;
            val.x = tile[n][q * 4 + 0];
            val.y = tile[n][q * 4 + 1];
            val.z = tile[n][q * 4 + 2];
            val.w = tile[n][q * 4 + 3];
            *(uint4*)(xTb + (size_t)n * C_ + q * 8) = val;
        }
        __syncthreads();              // tile reuse across it-loop
    }
}

// ---------------------------------------------------------------------------
// GENERAL PATH (device-gated on gamma != 0; exact no-op when gamma == 0).
// ---------------------------------------------------------------------------
__global__ __launch_bounds__(256) void proj_kernel(
    const u16* __restrict__ xT,
    const float* __restrict__ Wq, const float* __restrict__ bq,
    const float* __restrict__ Wk, const float* __restrict__ bk,
    const float* __restrict__ Wv, const float* __restrict__ bv,
    const float* __restrict__ gamma,
    u16* __restrict__ q, u16* __restrict__ k, u16* __restrict__ v)
{
    if (gamma[0] == 0.0f) return;
    for (int it = 0; it < 2; it++) {
        const int bid = it * 256 + blockIdx.x;
        const int b = bid >> 6;
        const int p = (bid & 63) * 64 + (threadIdx.x & 63);
        const int dg = threadIdx.x >> 6;
        const u16* xrow = xT + ((size_t)b * N_ + p) * C_;
        for (int d0 = dg * 160; d0 < dg * 160 + 160; d0++) {
            const float* wrow; float bias; u16* dst; int dd; int dim;
            if (d0 < 64)       { dd = d0;       wrow = Wq + (size_t)dd * C_; bias = bq[dd]; dst = q; dim = KD_; }
            else if (d0 < 128) { dd = d0 - 64;  wrow = Wk + (size_t)dd * C_; bias = bk[dd]; dst = k; dim = KD_; }
            else               { dd = d0 - 128; wrow = Wv + (size_t)dd * C_; bias = bv[dd]; dst = v; dim = VD_; }
            float s = bias;
            for (int c = 0; c < C_; c++) s += bf2f(xrow[c]) * wrow[c];
            dst[((size_t)b * dim + dd) * N_ + p] = f2bf(s);
        }
    }
}

__global__ __launch_bounds__(256) void attn_kernel(
    const u16* __restrict__ xT, const u16* __restrict__ q,
    const u16* __restrict__ k, const u16* __restrict__ v,
    const float* __restrict__ gamma, u16* __restrict__ yT)
{
    const float g = gamma[0];
    if (g == 0.0f) return;
    __shared__ float pls[4][64];
    const int wv = threadIdx.x >> 6, lane = threadIdx.x & 63;
    for (int it = 0; it < 4; it++) {
        const int bid = it * 256 + blockIdx.x;
        const int b  = bid >> 7;
        const int q0 = (bid & 127) * 32 + wv * 8;
        const u16* kb = k + (size_t)b * KD_ * N_;
        const u16* vb = v + (size_t)b * VD_ * N_;
        for (int qi = 0; qi < 8; qi++) {
            const int i = q0 + qi;
            const float qv = bf2f(q[((size_t)b * KD_ + lane) * N_ + i]);
            float mx = -1e30f, l = 0.f;
            for (int jb = 0; jb < N_; jb += 64) {
                float e = 0.f;
                for (int kd = 0; kd < 64; kd++)
                    e += __shfl(qv, kd) * bf2f(kb[(size_t)kd * N_ + jb + lane]);
                const float nm = fmaxf(mx, e);
                l = l * __expf(mx - nm) + __expf(e - nm);
                mx = nm;
            }
            for (int off = 32; off; off >>= 1) {
                const float mo = __shfl_xor(mx, off);
                const float lo = __shfl_xor(l, off);
                const float nm = fmaxf(mx, mo);
                l = l * __expf(mx - nm) + lo * __expf(mo - nm);
                mx = nm;
            }
            float oacc[8];
            #pragma unroll
            for (int r = 0; r < 8; r++) oacc[r] = 0.f;
            for (int jb = 0; jb < N_; jb += 64) {
                float e = 0.f;
                for (int kd = 0; kd < 64; kd++)
                    e += __shfl(qv, kd) * bf2f(kb[(size_t)kd * N_ + jb + lane]);
                __syncthreads();
                pls[wv][lane] = __expf(e - mx);
                __syncthreads();
                for (int jj = 0; jj < 64; jj++) {
                    const float p = pls[wv][jj];
                    #pragma unroll
                    for (int r = 0; r < 8; r++)
                        oacc[r] += p * bf2f(vb[(size_t)(r * 64 + lane) * N_ + jb + jj]);
                }
            }
            const float inv = 1.f / l;
            #pragma unroll
            for (int r = 0; r < 8; r++) {
                const size_t idx = ((size_t)b * N_ + i) * C_ + r * 64 + lane;
                yT[idx] = f2bf(g * oacc[r] * inv + bf2f(xT[idx]));
            }
        }
    }
}

// ---------------------------------------------------------------------------
// Fused GEMM: Out[b][o][n] = ReLU(BN(sum_c Wf[o][c] * A[b][n][c])),
// A = xT (gamma==0) or yT (gamma!=0), bf16 pixel-major [B][N][C].
// Round-6: single variable vs round 5 — A-prefetch depth 4 -> 8 sets.
// Round-5 diagnosis: wave-step wall ~1.8-3.6k cyc vs 80-cyc MFMA issue =
// vmcnt stall on the A set; depth-4 covers only ~3 steps. Depth-8 puts 32
// loads/wave in flight (~7 steps coverage). Regs ~222 incl acc, under the
// (256,2) 256-cap; spill tripwire = WRITE_SIZE >> 66 MB (round-3 lesson).
// ---------------------------------------------------------------------------
__global__ __launch_bounds__(256, 2) void gemm_bn_relu(
    const u16* __restrict__ xT, const u16* __restrict__ yT,
    const u16* __restrict__ Wf16, const float* __restrict__ gamma,
    const float* __restrict__ bnw, const float* __restrict__ bnb,
    const float* __restrict__ bnm, const float* __restrict__ bnv,
    float* __restrict__ out)
{
    __shared__ u16 lds_w[8 * 128 * 32];   // 64 KB: 8 K-tiles x [128o][32c]

    const int bid = blockIdx.x;
    const int pt8 = bid & 7;
    const int ot  = (bid >> 3) & 3;
    const int g   = bid >> 5;
    const int pt  = (g & 3) * 8 + pt8;
    const int b   = g >> 2;

    const int t = threadIdx.x;
    const int lane = t & 63;
    const int wv = t >> 6;
    const int wm = wv >> 1;
    const int wn = wv & 1;
    const int lcol = lane & 15;
    const int kq = lane >> 4;

    // W staging map (proven: 2-way max, free)
    const int rw = t >> 2, posw = t & 3;
    const int ql = (posw - swz(rw)) & 3;          // logical chunk to load
    const u16* WT0 = Wf16 + (size_t)(ot * 128 + rw) * C_ + ql * 8;
    const u16* WT1 = WT0 + (size_t)64 * C_;
    const int wla0 = rw * 32 + posw * 8;          // u16 LDS offsets
    const int wla1 = wla0 + 64 * 32;

    // B-frag read addresses within one 8KB tile (u16 units), step-invariant
    int baddr[4];
    #pragma unroll
    for (int i = 0; i < 4; i++) {
        const int R = wn * 64 + i * 16 + lcol;
        baddr[i] = R * 32 + ((kq + swz(R)) & 3) * 8;
    }

    // A-frag global bases: lane reads 8 consecutive bf16 along C
    const u16* Asrc = (gamma[0] == 0.0f) ? xT : yT;
    const u16* Ab[4];
    #pragma unroll
    for (int mi = 0; mi < 4; mi++)
        Ab[mi] = Asrc + ((size_t)b * N_ + pt * 128 + wm * 64 + mi * 16 + lcol) * C_ + kq * 8;

    f32x4 acc[4][4];
    #pragma unroll
    for (int i = 0; i < 4; i++)
        #pragma unroll
        for (int j = 0; j < 4; j++)
            acc[i][j] = (f32x4){0.f, 0.f, 0.f, 0.f};

    auto loadA = [&](bf16x8 (&d)[4], int ks) {
        #pragma unroll
        for (int mi = 0; mi < 4; mi++)
            d[mi] = *(const bf16x8*)(Ab[mi] + ks * 32);   // ks*64B folds into imm
    };
    auto stepf = [&](bf16x8 (&af)[4], int ks) {
        const int kt = ks & 7;
        bf16x8 bfg[4];
        #pragma unroll
        for (int ni = 0; ni < 4; ni++)
            bfg[ni] = *(const bf16x8*)&lds_w[kt * 4096 + baddr[ni]];
        #pragma unroll
        for (int mi = 0; mi < 4; mi++)
            #pragma unroll
            for (int ni = 0; ni < 4; ni++)
                acc[mi][ni] = __builtin_amdgcn_mfma_f32_16x16x32_bf16(
                    af[mi], bfg[ni], acc[mi][ni], 0, 0, 0);
    };
    auto stageW = [&](int half) {
        #pragma unroll
        for (int kt = 0; kt < 8; kt++) {
            const uint4 w0 = *(const uint4*)(WT0 + (half * 8 + kt) * 32);
            const uint4 w1 = *(const uint4*)(WT1 + (half * 8 + kt) * 32);
            *(uint4*)&lds_w[kt * 4096 + wla0] = w0;
            *(uint4*)&lds_w[kt * 4096 + wla1] = w1;
        }
    };

    // 8-set rotating A-prefetch (all indices compile-time; rule #20)
    bf16x8 s0[4], s1[4], s2[4], s3[4], s4[4], s5[4], s6[4], s7[4];
    loadA(s0, 0); loadA(s1, 1); loadA(s2, 2); loadA(s3, 3);
    loadA(s4, 4); loadA(s5, 5); loadA(s6, 6); loadA(s7, 7);
    stageW(0);
    tile_barrier();                 // W half 0 visible; A-loads stay in flight
    stepf(s0, 0);  loadA(s0, 8);
    stepf(s1, 1);  loadA(s1, 9);
    stepf(s2, 2);  loadA(s2, 10);
    stepf(s3, 3);  loadA(s3, 11);
    stepf(s4, 4);  loadA(s4, 12);
    stepf(s5, 5);  loadA(s5, 13);
    stepf(s6, 6);  loadA(s6, 14);
    stepf(s7, 7);  loadA(s7, 15);
    tile_barrier();                 // everyone done reading half 0
    stageW(1);
    tile_barrier();                 // W half 1 visible
    stepf(s0, 8);
    stepf(s1, 9);
    stepf(s2, 10);
    stepf(s3, 11);
    stepf(s4, 12);
    stepf(s5, 13);
    stepf(s6, 14);
    stepf(s7, 15);

    float scale[4], shift[4];
    #pragma unroll
    for (int ni = 0; ni < 4; ni++) {
        const int o = ot * 128 + wn * 64 + ni * 16 + lcol;
        const float s = bnw[o] * rsqrtf(bnv[o] + 1e-5f);
        scale[ni] = s;
        shift[ni] = bnb[o] - bnm[o] * s;
    }
    #pragma unroll
    for (int mi = 0; mi < 4; mi++) {
        const int npix = pt * 128 + wm * 64 + mi * 16 + kq * 4;
        #pragma unroll
        for (int ni = 0; ni < 4; ni++) {
            const int o = ot * 128 + wn * 64 + ni * 16 + lcol;
            f32x4 pk;
            #pragma unroll
            for (int r = 0; r < 4; r++)
                pk[r] = fmaxf(acc[mi][ni][r] * scale[ni] + shift[ni], 0.0f);
            *(f32x4*)(out + ((size_t)b * OD_ + o) * N_ + npix) = pk;
        }
    }
}

extern "C" void kernel_launch(void* const* d_in, const int* in_sizes, int n_in,
                              void* d_out, int out_size, void* d_ws, size_t ws_size,
                              hipStream_t stream) {
    const float* x     = (const float*)d_in[0];
    const float* Wq    = (const float*)d_in[1];
    const float* bq    = (const float*)d_in[2];
    const float* Wk    = (const float*)d_in[3];
    const float* bk    = (const float*)d_in[4];
    const float* Wv    = (const float*)d_in[5];
    const float* bv    = (const float*)d_in[6];
    const float* gamma = (const float*)d_in[7];
    const float* Wf    = (const float*)d_in[8];
    const float* bnw   = (const float*)d_in[9];
    const float* bnb   = (const float*)d_in[10];
    const float* bnm   = (const float*)d_in[11];
    const float* bnv   = (const float*)d_in[12];
    float* out = (float*)d_out;

    char* ws = (char*)d_ws;
    u16* Wf16 = (u16*)(ws);                  //     524,288 B (always)
    u16* xT   = (u16*)(ws + 524288);         // 33,554,432 B (always: gemm A-source)
    u16* yT   = (u16*)(ws + 34078720);       // 33,554,432 B (gated)
    u16* q    = (u16*)(ws + 67633152);       //  4,194,304 B (gated)
    u16* k    = (u16*)(ws + 71827456);       //  4,194,304 B (gated)
    u16* v    = (u16*)(ws + 76021760);       // 33,554,432 B (gated)

    transpose_convert_kernel<<<1040, 256, 0, stream>>>(x, Wf, xT, Wf16);
    proj_kernel<<<256, 256, 0, stream>>>(xT, Wq, bq, Wk, bk, Wv, bv, gamma, q, k, v);
    attn_kernel<<<256, 256, 0, stream>>>(xT, q, k, v, gamma, yT);
    gemm_bn_relu<<<1024, 256, 0, stream>>>(xT, yT, Wf16, gamma, bnw, bnb, bnm, bnv, out);
}

// Round 7
// 167.606 us; speedup vs baseline: 1.0719x; 1.0719x over previous
//
#include <hip/hip_runtime.h>
#include <hip/hip_bf16.h>

typedef unsigned short u16;
typedef unsigned int u32;
typedef __attribute__((ext_vector_type(8))) short bf16x8;
typedef __attribute__((ext_vector_type(4))) float f32x4;
typedef __attribute__((ext_vector_type(4))) u16 u16x4;

#define B_ 8
#define C_ 512
#define N_ 4096
#define KD_ 64
#define VD_ 512
#define OD_ 512

static __device__ __forceinline__ float bf2f(u16 u) {
    union { u32 i; float f; } z; z.i = ((u32)u) << 16; return z.f;
}
static __device__ __forceinline__ u16 f2bf(float f) {
    union { float f; u32 u; } v; v.f = f;
    u32 r = v.u + 0x7fffu + ((v.u >> 16) & 1u);
    return (u16)(r >> 16);
}
// pack bf16(lo), bf16(hi) into one u32 with round-half-up: 2 adds + 1 v_perm
static __device__ __forceinline__ u32 pkbf(float lo, float hi) {
    u32 ul = __float_as_uint(lo) + 0x8000u;
    u32 uh = __float_as_uint(hi) + 0x8000u;
    return __builtin_amdgcn_perm(uh, ul, 0x07060302u);
}
// chunk-rotation swizzle: logical chunk c of row r sits at position (c+swz(r))&3
static __device__ __forceinline__ int swz(int row) { return ((row >> 2) + (row >> 4)) & 3; }

// raw barrier: lgkm drain (my ds ops done) -> s_barrier. Global loads stay
// IN FLIGHT across it (no vmcnt(0) drain, unlike __syncthreads()).
static __device__ __forceinline__ void tile_barrier() {
    asm volatile("s_waitcnt lgkmcnt(0)" ::: "memory");
    __builtin_amdgcn_s_barrier();
    asm volatile("" ::: "memory");
}

// ---------------------------------------------------------------------------
// Blocks 256..271: Wf f32->bf16 (always needed). Blocks 0..255: x->xT
// transpose, ONLY for the gamma!=0 general path (device-gated) — the gemm
// fast path does its own in-block transpose again (round-7: the separate
// always-on transpose pass cost +19us and lost to the fused r4 total).
// ---------------------------------------------------------------------------
__global__ __launch_bounds__(256) void transpose_convert_kernel(
    const float* __restrict__ x, const float* __restrict__ Wf,
    const float* __restrict__ gamma,
    u16* __restrict__ xT, u16* __restrict__ Wf16)
{
    const int t = threadIdx.x;
    if (blockIdx.x >= 256) {
        const int tid = (blockIdx.x - 256) * 256 + t;
        const float4* src = (const float4*)Wf + (size_t)tid * 16;
        u16* dst = Wf16 + (size_t)tid * 64;
        #pragma unroll
        for (int j = 0; j < 16; j++) {
            const float4 f = src[j];
            u16x4 p;
            p[0] = f2bf(f.x); p[1] = f2bf(f.y); p[2] = f2bf(f.z); p[3] = f2bf(f.w);
            *(u16x4*)(dst + j * 4) = p;
        }
        return;
    }
    if (gamma[0] == 0.0f) return;     // fast path: xT not needed
    __shared__ u32 tile[64][33];
    for (int it = 0; it < 16; it++) {
        const int bid = it * 256 + blockIdx.x;
        const int nt = bid & 63;
        const int ct = (bid >> 6) & 7;
        const int b  = bid >> 9;
        const float* xb  = x  + ((size_t)b * C_ + ct * 64) * N_ + nt * 64;
        u16*         xTb = xT + ((size_t)b * N_ + nt * 64) * C_ + ct * 64;
        {
            const int p  = t >> 3;
            const int n8 = t & 7;
            const float* r0 = xb + (size_t)(2 * p)     * N_ + n8 * 8;
            const float* r1 = xb + (size_t)(2 * p + 1) * N_ + n8 * 8;
            const float4 a0 = *(const float4*)(r0);
            const float4 a1 = *(const float4*)(r0 + 4);
            const float4 c0 = *(const float4*)(r1);
            const float4 c1 = *(const float4*)(r1 + 4);
            const float av[8] = { a0.x, a0.y, a0.z, a0.w, a1.x, a1.y, a1.z, a1.w };
            const float cv[8] = { c0.x, c0.y, c0.z, c0.w, c1.x, c1.y, c1.z, c1.w };
            #pragma unroll
            for (int j = 0; j < 8; j++)
                tile[n8 * 8 + j][p] = (u32)f2bf(av[j]) | ((u32)f2bf(cv[j]) << 16);
        }
        __syncthreads();
        #pragma unroll
        for (int h = 0; h < 2; h++) {
            const int id = t + h * 256;
            const int n  = id >> 3;
            const int q  = id & 7;
            uint4 val;
            val.x = tile[n][q * 4 + 0];
            val.y = tile[n][q * 4 + 1];
            val.z = tile[n][q * 4 + 2];
            val.w = tile[n][q * 4 + 3];
            *(uint4*)(xTb + (size_t)n * C_ + q * 8) = val;
        }
        __syncthreads();              // tile reuse across it-loop
    }
}

// ---------------------------------------------------------------------------
// GENERAL PATH (device-gated on gamma != 0; exact no-op when gamma == 0).
// ---------------------------------------------------------------------------
__global__ __launch_bounds__(256) void proj_kernel(
    const u16* __restrict__ xT,
    const float* __restrict__ Wq, const float* __restrict__ bq,
    const float* __restrict__ Wk, const float* __restrict__ bk,
    const float* __restrict__ Wv, const float* __restrict__ bv,
    const float* __restrict__ gamma,
    u16* __restrict__ q, u16* __restrict__ k, u16* __restrict__ v)
{
    if (gamma[0] == 0.0f) return;
    for (int it = 0; it < 2; it++) {
        const int bid = it * 256 + blockIdx.x;
        const int b = bid >> 6;
        const int p = (bid & 63) * 64 + (threadIdx.x & 63);
        const int dg = threadIdx.x >> 6;
        const u16* xrow = xT + ((size_t)b * N_ + p) * C_;
        for (int d0 = dg * 160; d0 < dg * 160 + 160; d0++) {
            const float* wrow; float bias; u16* dst; int dd; int dim;
            if (d0 < 64)       { dd = d0;       wrow = Wq + (size_t)dd * C_; bias = bq[dd]; dst = q; dim = KD_; }
            else if (d0 < 128) { dd = d0 - 64;  wrow = Wk + (size_t)dd * C_; bias = bk[dd]; dst = k; dim = KD_; }
            else               { dd = d0 - 128; wrow = Wv + (size_t)dd * C_; bias = bv[dd]; dst = v; dim = VD_; }
            float s = bias;
            for (int c = 0; c < C_; c++) s += bf2f(xrow[c]) * wrow[c];
            dst[((size_t)b * dim + dd) * N_ + p] = f2bf(s);
        }
    }
}

__global__ __launch_bounds__(256) void attn_kernel(
    const u16* __restrict__ xT, const u16* __restrict__ q,
    const u16* __restrict__ k, const u16* __restrict__ v,
    const float* __restrict__ gamma, u16* __restrict__ yT)
{
    const float g = gamma[0];
    if (g == 0.0f) return;
    __shared__ float pls[4][64];
    const int wv = threadIdx.x >> 6, lane = threadIdx.x & 63;
    for (int it = 0; it < 4; it++) {
        const int bid = it * 256 + blockIdx.x;
        const int b  = bid >> 7;
        const int q0 = (bid & 127) * 32 + wv * 8;
        const u16* kb = k + (size_t)b * KD_ * N_;
        const u16* vb = v + (size_t)b * VD_ * N_;
        for (int qi = 0; qi < 8; qi++) {
            const int i = q0 + qi;
            const float qv = bf2f(q[((size_t)b * KD_ + lane) * N_ + i]);
            float mx = -1e30f, l = 0.f;
            for (int jb = 0; jb < N_; jb += 64) {
                float e = 0.f;
                for (int kd = 0; kd < 64; kd++)
                    e += __shfl(qv, kd) * bf2f(kb[(size_t)kd * N_ + jb + lane]);
                const float nm = fmaxf(mx, e);
                l = l * __expf(mx - nm) + __expf(e - nm);
                mx = nm;
            }
            for (int off = 32; off; off >>= 1) {
                const float mo = __shfl_xor(mx, off);
                const float lo = __shfl_xor(l, off);
                const float nm = fmaxf(mx, mo);
                l = l * __expf(mx - nm) + lo * __expf(mo - nm);
                mx = nm;
            }
            float oacc[8];
            #pragma unroll
            for (int r = 0; r < 8; r++) oacc[r] = 0.f;
            for (int jb = 0; jb < N_; jb += 64) {
                float e = 0.f;
                for (int kd = 0; kd < 64; kd++)
                    e += __shfl(qv, kd) * bf2f(kb[(size_t)kd * N_ + jb + lane]);
                __syncthreads();
                pls[wv][lane] = __expf(e - mx);
                __syncthreads();
                for (int jj = 0; jj < 64; jj++) {
                    const float p = pls[wv][jj];
                    #pragma unroll
                    for (int r = 0; r < 8; r++)
                        oacc[r] += p * bf2f(vb[(size_t)(r * 64 + lane) * N_ + jb + jj]);
                }
            }
            const float inv = 1.f / l;
            #pragma unroll
            for (int r = 0; r < 8; r++) {
                const size_t idx = ((size_t)b * N_ + i) * C_ + r * 64 + lane;
                yT[idx] = f2bf(g * oacc[r] * inv + bf2f(xT[idx]));
            }
        }
    }
}

// ---------------------------------------------------------------------------
// Fused GEMM: Out[b][o][n] = ReLU(BN(sum_c Wf[o][c] * x[b][c][n])).
// Round-7 restructure (diagnosis from r5/r6: rate-bound, not latency-bound;
// the r5/r6 split paid an extra full pass over x):
//  - block = 64 px x ALL 512 outputs. A-panel (64px x 512C bf16 = 64KB) is
//    LDS-resident: 16 proven-swizzle K-tiles, staged ONCE per block from x
//    f32 (in-block transpose, r4's proven maps). x read EXACTLY once/kernel.
//  - W streams global->reg as contiguous b128 frags (Wf16 is o-major: frag
//    = 16 consecutive bytes, no transpose), double-buffered per K-step.
//  - K-loop: ZERO ds_writes steady-state, 2 barriers per block total.
//  - tiles 8..15 staged T14-style (loads issued early, writes after the
//    compute of the matching half-0 step) under half-0's MFMAs.
//  - 512 blocks (2/CU, one generation); stage/compute/store overlap
//    between the two residents.
// ---------------------------------------------------------------------------
__global__ __launch_bounds__(256, 2) void gemm_bn_relu(
    const float* __restrict__ x, const u16* __restrict__ yT,
    const u16* __restrict__ Wf16, const float* __restrict__ gamma,
    const float* __restrict__ bnw, const float* __restrict__ bnb,
    const float* __restrict__ bnm, const float* __restrict__ bnv,
    float* __restrict__ out)
{
    __shared__ u16 lds_a[16 * 64 * 32];   // 64 KB: 16 K-tiles x [64px][32c]

    const int bid = blockIdx.x;           // 512 = 8 b x 64 pt
    const int b  = bid >> 6;
    const int pt = bid & 63;

    const int t = threadIdx.x;
    const int lane = t & 63;
    const int wn = t >> 6;                // wave owns o-range wn*128..+127
    const int lcol = lane & 15;
    const int kq = lane >> 4;

    // A-frag LDS read addrs (u16 units within a 4KB tile), step-invariant
    int aaddr[4];
    #pragma unroll
    for (int mi = 0; mi < 4; mi++) {
        const int P = mi * 16 + lcol;
        aaddr[mi] = P * 32 + ((kq + swz(P)) & 3) * 8;
    }

    // W frag addressing: uniform base per wave + 32-bit lane offsets
    const u16* Wbase = Wf16 + (size_t)(wn * 128) * C_;
    u32 woff[8];
    #pragma unroll
    for (int ni = 0; ni < 8; ni++)
        woff[ni] = (u32)(ni * 16 + lcol) * C_ + kq * 8;

    f32x4 acc[4][8];
    #pragma unroll
    for (int i = 0; i < 4; i++)
        #pragma unroll
        for (int j = 0; j < 8; j++)
            acc[i][j] = (f32x4){0.f, 0.f, 0.f, 0.f};

    bf16x8 w0[8], w1[8];
    auto loadW0 = [&](int ks) {
        #pragma unroll
        for (int ni = 0; ni < 8; ni++)
            w0[ni] = *(const bf16x8*)(Wbase + woff[ni] + ks * 32);
    };
    auto loadW1 = [&](int ks) {
        #pragma unroll
        for (int ni = 0; ni < 8; ni++)
            w1[ni] = *(const bf16x8*)(Wbase + woff[ni] + ks * 32);
    };
    auto computeK = [&](bf16x8 (&w)[8], int ks) {
        bf16x8 af[4];
        #pragma unroll
        for (int mi = 0; mi < 4; mi++)
            af[mi] = *(const bf16x8*)&lds_a[ks * 2048 + aaddr[mi]];
        #pragma unroll
        for (int mi = 0; mi < 4; mi++)
            #pragma unroll
            for (int ni = 0; ni < 8; ni++)
                acc[mi][ni] = __builtin_amdgcn_mfma_f32_16x16x32_bf16(
                    af[mi], w[ni], acc[mi][ni], 0, 0, 0);
    };

    if (gamma[0] == 0.0f) {
        // ---- fast path: in-block transpose of x f32 -> swizzled bf16 tiles ----
        const int q4 = t & 15, cp = t >> 4;            // c-pair 0..15 within tile
        int xidx[4];                                    // dword indices in tile
        #pragma unroll
        for (int j = 0; j < 4; j++) {
            const int p = q4 + 16 * j;                 // proven map: p&1 varies
            xidx[j] = p * 16 + (((cp >> 2) + swz(p)) & 3) * 4 + (cp & 3);
        }
        float evA[4], ovA[4], evB[4], ovB[4];
        auto sloadA = [&](int kt) {
            const float* e = x + ((size_t)(b * C_ + kt * 32 + 2 * cp)) * N_ + pt * 64 + q4;
            const float* o = e + N_;
            #pragma unroll
            for (int j = 0; j < 4; j++) { evA[j] = e[16 * j]; ovA[j] = o[16 * j]; }
        };
        auto sloadB = [&](int kt) {
            const float* e = x + ((size_t)(b * C_ + kt * 32 + 2 * cp)) * N_ + pt * 64 + q4;
            const float* o = e + N_;
            #pragma unroll
            for (int j = 0; j < 4; j++) { evB[j] = e[16 * j]; ovB[j] = o[16 * j]; }
        };
        auto swriteA = [&](int kt) {
            u32* lx = (u32*)lds_a + kt * 1024;
            #pragma unroll
            for (int j = 0; j < 4; j++) lx[xidx[j]] = pkbf(evA[j], ovA[j]);
        };
        auto swriteB = [&](int kt) {
            u32* lx = (u32*)lds_a + kt * 1024;
            #pragma unroll
            for (int j = 0; j < 4; j++) lx[xidx[j]] = pkbf(evB[j], ovB[j]);
        };

        loadW0(0); loadW1(1);
        // stage tiles 0..7, 2-deep rolling (write k overlaps load k+1)
        sloadA(0);
        sloadB(1); swriteA(0);
        sloadA(2); swriteB(1);
        sloadB(3); swriteA(2);
        sloadA(4); swriteB(3);
        sloadB(5); swriteA(4);
        sloadA(6); swriteB(5);
        sloadB(7); swriteA(6);
        swriteB(7);
        sloadA(8);                      // tile-8 loads in flight across barrier
        tile_barrier();
        // half 0: compute 0..7; stage tiles 8..15 under the MFMAs (T14)
        computeK(w0, 0); loadW0(2); swriteA(8);  sloadB(9);
        computeK(w1, 1); loadW1(3); swriteB(9);  sloadA(10);
        computeK(w0, 2); loadW0(4); swriteA(10); sloadB(11);
        computeK(w1, 3); loadW1(5); swriteB(11); sloadA(12);
        computeK(w0, 4); loadW0(6); swriteA(12); sloadB(13);
        computeK(w1, 5); loadW1(7); swriteB(13); sloadA(14);
        computeK(w0, 6); loadW0(8); swriteA(14); sloadB(15);
        computeK(w1, 7); loadW1(9); swriteB(15);
        tile_barrier();
        // half 1: pure compute + W ping-pong
        computeK(w0, 8);  loadW0(10);
        computeK(w1, 9);  loadW1(11);
        computeK(w0, 10); loadW0(12);
        computeK(w1, 11); loadW1(13);
        computeK(w0, 12); loadW0(14);
        computeK(w1, 13); loadW1(15);
        computeK(w0, 14);
        computeK(w1, 15);
    } else {
        // ---- general path: stage panel from yT (bf16 pixel-major), same
        //      swizzled tile layout via uint4 copies ----
        const int p = t >> 2, pos = t & 3;
        const int ql = (pos - swz(p)) & 3;
        const u16* Ysrc = yT + ((size_t)b * N_ + pt * 64 + p) * C_ + ql * 8;
        const int yla = p * 32 + pos * 8;              // u16 offset within tile
        uint4 yA, yB;
        auto sloadA = [&](int kt) { yA = *(const uint4*)(Ysrc + kt * 32); };
        auto sloadB = [&](int kt) { yB = *(const uint4*)(Ysrc + kt * 32); };
        auto swriteA = [&](int kt) { *(uint4*)&lds_a[kt * 2048 + yla] = yA; };
        auto swriteB = [&](int kt) { *(uint4*)&lds_a[kt * 2048 + yla] = yB; };

        loadW0(0); loadW1(1);
        sloadA(0);
        sloadB(1); swriteA(0);
        sloadA(2); swriteB(1);
        sloadB(3); swriteA(2);
        sloadA(4); swriteB(3);
        sloadB(5); swriteA(4);
        sloadA(6); swriteB(5);
        sloadB(7); swriteA(6);
        swriteB(7);
        sloadA(8);
        tile_barrier();
        computeK(w0, 0); loadW0(2); swriteA(8);  sloadB(9);
        computeK(w1, 1); loadW1(3); swriteB(9);  sloadA(10);
        computeK(w0, 2); loadW0(4); swriteA(10); sloadB(11);
        computeK(w1, 3); loadW1(5); swriteB(11); sloadA(12);
        computeK(w0, 4); loadW0(6); swriteA(12); sloadB(13);
        computeK(w1, 5); loadW1(7); swriteB(13); sloadA(14);
        computeK(w0, 6); loadW0(8); swriteA(14); sloadB(15);
        computeK(w1, 7); loadW1(9); swriteB(15);
        tile_barrier();
        computeK(w0, 8);  loadW0(10);
        computeK(w1, 9);  loadW1(11);
        computeK(w0, 10); loadW0(12);
        computeK(w1, 11); loadW1(13);
        computeK(w0, 12); loadW0(14);
        computeK(w1, 13); loadW1(15);
        computeK(w0, 14);
        computeK(w1, 15);
    }

    float scale[8], shift[8];
    #pragma unroll
    for (int ni = 0; ni < 8; ni++) {
        const int o = wn * 128 + ni * 16 + lcol;
        const float s = bnw[o] * rsqrtf(bnv[o] + 1e-5f);
        scale[ni] = s;
        shift[ni] = bnb[o] - bnm[o] * s;
    }
    #pragma unroll
    for (int mi = 0; mi < 4; mi++) {
        const int npix = pt * 64 + mi * 16 + kq * 4;
        #pragma unroll
        for (int ni = 0; ni < 8; ni++) {
            const int o = wn * 128 + ni * 16 + lcol;
            f32x4 pk;
            #pragma unroll
            for (int r = 0; r < 4; r++)
                pk[r] = fmaxf(acc[mi][ni][r] * scale[ni] + shift[ni], 0.0f);
            *(f32x4*)(out + ((size_t)b * OD_ + o) * N_ + npix) = pk;
        }
    }
}

extern "C" void kernel_launch(void* const* d_in, const int* in_sizes, int n_in,
                              void* d_out, int out_size, void* d_ws, size_t ws_size,
                              hipStream_t stream) {
    const float* x     = (const float*)d_in[0];
    const float* Wq    = (const float*)d_in[1];
    const float* bq    = (const float*)d_in[2];
    const float* Wk    = (const float*)d_in[3];
    const float* bk    = (const float*)d_in[4];
    const float* Wv    = (const float*)d_in[5];
    const float* bv    = (const float*)d_in[6];
    const float* gamma = (const float*)d_in[7];
    const float* Wf    = (const float*)d_in[8];
    const float* bnw   = (const float*)d_in[9];
    const float* bnb   = (const float*)d_in[10];
    const float* bnm   = (const float*)d_in[11];
    const float* bnv   = (const float*)d_in[12];
    float* out = (float*)d_out;

    char* ws = (char*)d_ws;
    u16* Wf16 = (u16*)(ws);                  //     524,288 B (always)
    u16* xT   = (u16*)(ws + 524288);         // 33,554,432 B (gated: gamma!=0)
    u16* yT   = (u16*)(ws + 34078720);       // 33,554,432 B (gated)
    u16* q    = (u16*)(ws + 67633152);       //  4,194,304 B (gated)
    u16* k    = (u16*)(ws + 71827456);       //  4,194,304 B (gated)
    u16* v    = (u16*)(ws + 76021760);       // 33,554,432 B (gated)

    transpose_convert_kernel<<<272, 256, 0, stream>>>(x, Wf, gamma, xT, Wf16);
    proj_kernel<<<256, 256, 0, stream>>>(xT, Wq, bq, Wk, bk, Wv, bv, gamma, q, k, v);
    attn_kernel<<<256, 256, 0, stream>>>(xT, q, k, v, gamma, yT);
    gemm_bn_relu<<<512, 256, 0, stream>>>(x, yT, Wf16, gamma, bnw, bnb, bnm, bnv, out);
}

// Round 8
// 164.817 us; speedup vs baseline: 1.0901x; 1.0169x over previous
//
#include <hip/hip_runtime.h>
#include <hip/hip_bf16.h>

typedef unsigned short u16;
typedef unsigned int u32;
typedef __attribute__((ext_vector_type(8))) short bf16x8;
typedef __attribute__((ext_vector_type(4))) float f32x4;
typedef __attribute__((ext_vector_type(4))) u16 u16x4;

#define B_ 8
#define C_ 512
#define N_ 4096
#define KD_ 64
#define VD_ 512
#define OD_ 512

static __device__ __forceinline__ float bf2f(u16 u) {
    union { u32 i; float f; } z; z.i = ((u32)u) << 16; return z.f;
}
static __device__ __forceinline__ u16 f2bf(float f) {
    union { float f; u32 u; } v; v.f = f;
    u32 r = v.u + 0x7fffu + ((v.u >> 16) & 1u);
    return (u16)(r >> 16);
}
// chunk-rotation swizzle: logical chunk c of row r sits at position (c+swz(r))&3
static __device__ __forceinline__ int swz(int row) { return ((row >> 2) + (row >> 4)) & 3; }

// async global->LDS, 16B per lane: LDS dest = wave-uniform base + lane*16,
// global src = per-lane address. Completion tracked by vmcnt; __syncthreads'
// vmcnt(0) drain makes the data visible (m97 pattern).
static __device__ __forceinline__ void gld16(const u16* g, u16* l) {
    __builtin_amdgcn_global_load_lds(
        (const __attribute__((address_space(1))) void*)(const void*)g,
        (__attribute__((address_space(3))) void*)(void*)l,
        16, 0, 0);
}

// ---------------------------------------------------------------------------
// Blocks >= 1024: Wf f32->bf16 (always). Blocks 0..1023: x -> xT transpose
// (bf16, pixel-major [B][N][C]) — always-on: gemm consumes xT (or yT) as a
// pure-bf16 A operand so staging can use global_load_lds (no VGPR roundtrip).
// ---------------------------------------------------------------------------
__global__ __launch_bounds__(256) void transpose_convert_kernel(
    const float* __restrict__ x, const float* __restrict__ Wf,
    u16* __restrict__ xT, u16* __restrict__ Wf16)
{
    const int t = threadIdx.x;
    if (blockIdx.x >= 1024) {
        const int tid = (blockIdx.x - 1024) * 256 + t;
        const float4* src = (const float4*)Wf + (size_t)tid * 16;
        u16* dst = Wf16 + (size_t)tid * 64;
        #pragma unroll
        for (int j = 0; j < 16; j++) {
            const float4 f = src[j];
            u16x4 p;
            p[0] = f2bf(f.x); p[1] = f2bf(f.y); p[2] = f2bf(f.z); p[3] = f2bf(f.w);
            *(u16x4*)(dst + j * 4) = p;
        }
        return;
    }
    __shared__ u32 tile[64][33];
    for (int it = 0; it < 4; it++) {
        const int bid = it * 1024 + blockIdx.x;
        const int nt = bid & 63;
        const int ct = (bid >> 6) & 7;
        const int b  = bid >> 9;
        const float* xb  = x  + ((size_t)b * C_ + ct * 64) * N_ + nt * 64;
        u16*         xTb = xT + ((size_t)b * N_ + nt * 64) * C_ + ct * 64;
        {
            const int p  = t >> 3;
            const int n8 = t & 7;
            const float* r0 = xb + (size_t)(2 * p)     * N_ + n8 * 8;
            const float* r1 = xb + (size_t)(2 * p + 1) * N_ + n8 * 8;
            const float4 a0 = *(const float4*)(r0);
            const float4 a1 = *(const float4*)(r0 + 4);
            const float4 c0 = *(const float4*)(r1);
            const float4 c1 = *(const float4*)(r1 + 4);
            const float av[8] = { a0.x, a0.y, a0.z, a0.w, a1.x, a1.y, a1.z, a1.w };
            const float cv[8] = { c0.x, c0.y, c0.z, c0.w, c1.x, c1.y, c1.z, c1.w };
            #pragma unroll
            for (int j = 0; j < 8; j++)
                tile[n8 * 8 + j][p] = (u32)f2bf(av[j]) | ((u32)f2bf(cv[j]) << 16);
        }
        __syncthreads();
        #pragma unroll
        for (int h = 0; h < 2; h++) {
            const int id = t + h * 256;
            const int n  = id >> 3;
            const int q  = id & 7;
            uint4 val;
            val.x = tile[n][q * 4 + 0];
            val.y = tile[n][q * 4 + 1];
            val.z = tile[n][q * 4 + 2];
            val.w = tile[n][q * 4 + 3];
            *(uint4*)(xTb + (size_t)n * C_ + q * 8) = val;
        }
        __syncthreads();              // tile reuse across it-loop
    }
}

// ---------------------------------------------------------------------------
// GENERAL PATH (device-gated on gamma != 0; exact no-op when gamma == 0).
// ---------------------------------------------------------------------------
__global__ __launch_bounds__(256) void proj_kernel(
    const u16* __restrict__ xT,
    const float* __restrict__ Wq, const float* __restrict__ bq,
    const float* __restrict__ Wk, const float* __restrict__ bk,
    const float* __restrict__ Wv, const float* __restrict__ bv,
    const float* __restrict__ gamma,
    u16* __restrict__ q, u16* __restrict__ k, u16* __restrict__ v)
{
    if (gamma[0] == 0.0f) return;
    for (int it = 0; it < 2; it++) {
        const int bid = it * 256 + blockIdx.x;
        const int b = bid >> 6;
        const int p = (bid & 63) * 64 + (threadIdx.x & 63);
        const int dg = threadIdx.x >> 6;
        const u16* xrow = xT + ((size_t)b * N_ + p) * C_;
        for (int d0 = dg * 160; d0 < dg * 160 + 160; d0++) {
            const float* wrow; float bias; u16* dst; int dd; int dim;
            if (d0 < 64)       { dd = d0;       wrow = Wq + (size_t)dd * C_; bias = bq[dd]; dst = q; dim = KD_; }
            else if (d0 < 128) { dd = d0 - 64;  wrow = Wk + (size_t)dd * C_; bias = bk[dd]; dst = k; dim = KD_; }
            else               { dd = d0 - 128; wrow = Wv + (size_t)dd * C_; bias = bv[dd]; dst = v; dim = VD_; }
            float s = bias;
            for (int c = 0; c < C_; c++) s += bf2f(xrow[c]) * wrow[c];
            dst[((size_t)b * dim + dd) * N_ + p] = f2bf(s);
        }
    }
}

__global__ __launch_bounds__(256) void attn_kernel(
    const u16* __restrict__ xT, const u16* __restrict__ q,
    const u16* __restrict__ k, const u16* __restrict__ v,
    const float* __restrict__ gamma, u16* __restrict__ yT)
{
    const float g = gamma[0];
    if (g == 0.0f) return;
    __shared__ float pls[4][64];
    const int wv = threadIdx.x >> 6, lane = threadIdx.x & 63;
    for (int it = 0; it < 4; it++) {
        const int bid = it * 256 + blockIdx.x;
        const int b  = bid >> 7;
        const int q0 = (bid & 127) * 32 + wv * 8;
        const u16* kb = k + (size_t)b * KD_ * N_;
        const u16* vb = v + (size_t)b * VD_ * N_;
        for (int qi = 0; qi < 8; qi++) {
            const int i = q0 + qi;
            const float qv = bf2f(q[((size_t)b * KD_ + lane) * N_ + i]);
            float mx = -1e30f, l = 0.f;
            for (int jb = 0; jb < N_; jb += 64) {
                float e = 0.f;
                for (int kd = 0; kd < 64; kd++)
                    e += __shfl(qv, kd) * bf2f(kb[(size_t)kd * N_ + jb + lane]);
                const float nm = fmaxf(mx, e);
                l = l * __expf(mx - nm) + __expf(e - nm);
                mx = nm;
            }
            for (int off = 32; off; off >>= 1) {
                const float mo = __shfl_xor(mx, off);
                const float lo = __shfl_xor(l, off);
                const float nm = fmaxf(mx, mo);
                l = l * __expf(mx - nm) + lo * __expf(mo - nm);
                mx = nm;
            }
            float oacc[8];
            #pragma unroll
            for (int r = 0; r < 8; r++) oacc[r] = 0.f;
            for (int jb = 0; jb < N_; jb += 64) {
                float e = 0.f;
                for (int kd = 0; kd < 64; kd++)
                    e += __shfl(qv, kd) * bf2f(kb[(size_t)kd * N_ + jb + lane]);
                __syncthreads();
                pls[wv][lane] = __expf(e - mx);
                __syncthreads();
                for (int jj = 0; jj < 64; jj++) {
                    const float p = pls[wv][jj];
                    #pragma unroll
                    for (int r = 0; r < 8; r++)
                        oacc[r] += p * bf2f(vb[(size_t)(r * 64 + lane) * N_ + jb + jj]);
                }
            }
            const float inv = 1.f / l;
            #pragma unroll
            for (int r = 0; r < 8; r++) {
                const size_t idx = ((size_t)b * N_ + i) * C_ + r * 64 + lane;
                yT[idx] = f2bf(g * oacc[r] * inv + bf2f(xT[idx]));
            }
        }
    }
}

// ---------------------------------------------------------------------------
// Fused GEMM: Out[b][o][n] = ReLU(BN(sum_c Wf[o][c] * A[b][n][c])),
// A = xT (gamma==0) or yT (gamma!=0), bf16 pixel-major [B][N][C].
// Round-8: m97-faithful structure (the 912 TF-verified kernel shape):
//  - 128px x 128o tile, BK=32, 16 K-steps, single-buffered LDS (16KB).
//  - staging via global_load_lds width=16 (4 instrs/thread/step): LDS dest
//    LINEAR (wave-uniform base + lane*16B), per-lane GLOBAL source carries
//    the inverse chunk-rotation; ds_read_b128 applies the forward rotation
//    (rule #21 both-sides form; the exact swizzle pair proven in r0-r4).
//  - 2x __syncthreads per step (vmcnt(0) drain at barrier-1 lands the async
//    loads). No VGPR staging, no pack-VALU in the loop.
//  - (256,3): ~50 arch VGPR + 64 acc, 3 blocks/CU. XCD-grouped decode: the
//    4 o-blocks of one pixel-tile are adjacent -> same XCD L2 reuses the
//    A-panel; W (512KB bf16) is L2-resident everywhere.
// ---------------------------------------------------------------------------
__global__ __launch_bounds__(256, 3) void gemm_bn_relu(
    const u16* __restrict__ xT, const u16* __restrict__ yT,
    const u16* __restrict__ Wf16, const float* __restrict__ gamma,
    const float* __restrict__ bnw, const float* __restrict__ bnb,
    const float* __restrict__ bnm, const float* __restrict__ bnv,
    float* __restrict__ out)
{
    __shared__ u16 lds_a[128 * 32];
    __shared__ u16 lds_b[128 * 32];

    // bijective XCD swizzle (1024 % 8 == 0), then ot-minor decode
    const int wg = (blockIdx.x & 7) * 128 + (blockIdx.x >> 3);
    const int ot = wg & 3;
    const int mt = wg >> 2;                // 256 pixel-tiles
    const int b  = mt >> 5;
    const int px0 = (mt & 31) * 128;

    const int t = threadIdx.x;
    const int lane = t & 63;
    const int wv = t >> 6;
    const int wm = wv >> 1;
    const int wn = wv & 1;
    const int lcol = lane & 15;
    const int kq = lane >> 4;

    // staging decode: LDS slot s -> (row = s>>2, chunk-pos = s&3);
    // instr0 covers slots 0..255 (rows 0..63), instr1 slots 256..511.
    const int rs = t >> 2, ps = t & 3;
    const int ql = (ps - swz(rs)) & 3;     // logical chunk this slot holds
    const u16* Asrc = (gamma[0] == 0.0f) ? xT : yT;
    const u16* ga0 = Asrc + ((size_t)(b * N_ + px0 + rs)) * C_ + ql * 8;
    const u16* ga1 = ga0 + (size_t)64 * C_;
    const u16* gb0 = Wf16 + ((size_t)(ot * 128 + rs)) * C_ + ql * 8;
    const u16* gb1 = gb0 + (size_t)64 * C_;
    u16* la0 = lds_a + wv * 512;           // wave-uniform LDS bases
    u16* la1 = lds_a + 2048 + wv * 512;
    u16* lb0 = lds_b + wv * 512;
    u16* lb1 = lds_b + 2048 + wv * 512;

    // frag read addresses (u16 units), forward-rotated chunk
    int aaddr[4], baddr[4];
    #pragma unroll
    for (int i = 0; i < 4; i++) {
        const int P = wm * 64 + i * 16 + lcol;
        aaddr[i] = P * 32 + ((kq + swz(P)) & 3) * 8;
        const int R = wn * 64 + i * 16 + lcol;
        baddr[i] = R * 32 + ((kq + swz(R)) & 3) * 8;
    }

    f32x4 acc[4][4];
    #pragma unroll
    for (int i = 0; i < 4; i++)
        #pragma unroll
        for (int j = 0; j < 4; j++)
            acc[i][j] = (f32x4){0.f, 0.f, 0.f, 0.f};

    #pragma unroll
    for (int ks = 0; ks < 16; ++ks) {
        gld16(ga0 + ks * 32, la0);
        gld16(ga1 + ks * 32, la1);
        gld16(gb0 + ks * 32, lb0);
        gld16(gb1 + ks * 32, lb1);
        __syncthreads();               // vmcnt(0) drain: tiles landed
        bf16x8 af[4], bfg[4];
        #pragma unroll
        for (int mi = 0; mi < 4; mi++)
            af[mi] = *(const bf16x8*)&lds_a[aaddr[mi]];
        #pragma unroll
        for (int ni = 0; ni < 4; ni++)
            bfg[ni] = *(const bf16x8*)&lds_b[baddr[ni]];
        #pragma unroll
        for (int mi = 0; mi < 4; mi++)
            #pragma unroll
            for (int ni = 0; ni < 4; ni++)
                acc[mi][ni] = __builtin_amdgcn_mfma_f32_16x16x32_bf16(
                    af[mi], bfg[ni], acc[mi][ni], 0, 0, 0);
        __syncthreads();               // all reads done before next overwrite
    }

    float scale[4], shift[4];
    #pragma unroll
    for (int ni = 0; ni < 4; ni++) {
        const int o = ot * 128 + wn * 64 + ni * 16 + lcol;
        const float s = bnw[o] * rsqrtf(bnv[o] + 1e-5f);
        scale[ni] = s;
        shift[ni] = bnb[o] - bnm[o] * s;
    }
    #pragma unroll
    for (int mi = 0; mi < 4; mi++) {
        const int npix = px0 + wm * 64 + mi * 16 + kq * 4;
        #pragma unroll
        for (int ni = 0; ni < 4; ni++) {
            const int o = ot * 128 + wn * 64 + ni * 16 + lcol;
            f32x4 pk;
            #pragma unroll
            for (int r = 0; r < 4; r++)
                pk[r] = fmaxf(acc[mi][ni][r] * scale[ni] + shift[ni], 0.0f);
            *(f32x4*)(out + ((size_t)b * OD_ + o) * N_ + npix) = pk;
        }
    }
}

extern "C" void kernel_launch(void* const* d_in, const int* in_sizes, int n_in,
                              void* d_out, int out_size, void* d_ws, size_t ws_size,
                              hipStream_t stream) {
    const float* x     = (const float*)d_in[0];
    const float* Wq    = (const float*)d_in[1];
    const float* bq    = (const float*)d_in[2];
    const float* Wk    = (const float*)d_in[3];
    const float* bk    = (const float*)d_in[4];
    const float* Wv    = (const float*)d_in[5];
    const float* bv    = (const float*)d_in[6];
    const float* gamma = (const float*)d_in[7];
    const float* Wf    = (const float*)d_in[8];
    const float* bnw   = (const float*)d_in[9];
    const float* bnb   = (const float*)d_in[10];
    const float* bnm   = (const float*)d_in[11];
    const float* bnv   = (const float*)d_in[12];
    float* out = (float*)d_out;

    char* ws = (char*)d_ws;
    u16* Wf16 = (u16*)(ws);                  //     524,288 B (always)
    u16* xT   = (u16*)(ws + 524288);         // 33,554,432 B (always: gemm A-source)
    u16* yT   = (u16*)(ws + 34078720);       // 33,554,432 B (gated)
    u16* q    = (u16*)(ws + 67633152);       //  4,194,304 B (gated)
    u16* k    = (u16*)(ws + 71827456);       //  4,194,304 B (gated)
    u16* v    = (u16*)(ws + 76021760);       // 33,554,432 B (gated)

    transpose_convert_kernel<<<1040, 256, 0, stream>>>(x, Wf, xT, Wf16);
    proj_kernel<<<256, 256, 0, stream>>>(xT, Wq, bq, Wk, bk, Wv, bv, gamma, q, k, v);
    attn_kernel<<<256, 256, 0, stream>>>(xT, q, k, v, gamma, yT);
    gemm_bn_relu<<<1024, 256, 0, stream>>>(xT, yT, Wf16, gamma, bnw, bnb, bnm, bnv, out);
}

// Round 9
// 162.745 us; speedup vs baseline: 1.1039x; 1.0127x over previous
//
#include <hip/hip_runtime.h>
#include <hip/hip_bf16.h>

typedef unsigned short u16;
typedef unsigned int u32;
typedef __attribute__((ext_vector_type(8))) short bf16x8;
typedef __attribute__((ext_vector_type(4))) float f32x4;
typedef __attribute__((ext_vector_type(4))) u16 u16x4;

#define B_ 8
#define C_ 512
#define N_ 4096
#define KD_ 64
#define VD_ 512
#define OD_ 512

static __device__ __forceinline__ float bf2f(u16 u) {
    union { u32 i; float f; } z; z.i = ((u32)u) << 16; return z.f;
}
static __device__ __forceinline__ u16 f2bf(float f) {
    union { float f; u32 u; } v; v.f = f;
    u32 r = v.u + 0x7fffu + ((v.u >> 16) & 1u);
    return (u16)(r >> 16);
}
// chunk-rotation swizzle: logical chunk c of row r sits at position (c+swz(r))&3
static __device__ __forceinline__ int swz(int row) { return ((row >> 2) + (row >> 4)) & 3; }

// async global->LDS, 16B per lane: LDS dest = wave-uniform base + lane*16,
// global src = per-lane address. Completion tracked by vmcnt; __syncthreads'
// vmcnt(0) drain makes the data visible (m97 pattern).
static __device__ __forceinline__ void gld16(const u16* g, u16* l) {
    __builtin_amdgcn_global_load_lds(
        (const __attribute__((address_space(1))) void*)(const void*)g,
        (__attribute__((address_space(3))) void*)(void*)l,
        16, 0, 0);
}

// ---------------------------------------------------------------------------
// Blocks >= 1024: Wf f32->bf16 (always). Blocks 0..1023: x -> xT transpose
// (bf16, pixel-major [B][N][C]) — always-on: gemm consumes xT (or yT) as a
// pure-bf16 A operand so staging can use global_load_lds (no VGPR roundtrip).
// ---------------------------------------------------------------------------
__global__ __launch_bounds__(256) void transpose_convert_kernel(
    const float* __restrict__ x, const float* __restrict__ Wf,
    u16* __restrict__ xT, u16* __restrict__ Wf16)
{
    const int t = threadIdx.x;
    if (blockIdx.x >= 1024) {
        const int tid = (blockIdx.x - 1024) * 256 + t;
        const float4* src = (const float4*)Wf + (size_t)tid * 16;
        u16* dst = Wf16 + (size_t)tid * 64;
        #pragma unroll
        for (int j = 0; j < 16; j++) {
            const float4 f = src[j];
            u16x4 p;
            p[0] = f2bf(f.x); p[1] = f2bf(f.y); p[2] = f2bf(f.z); p[3] = f2bf(f.w);
            *(u16x4*)(dst + j * 4) = p;
        }
        return;
    }
    __shared__ u32 tile[64][33];
    for (int it = 0; it < 4; it++) {
        const int bid = it * 1024 + blockIdx.x;
        const int nt = bid & 63;
        const int ct = (bid >> 6) & 7;
        const int b  = bid >> 9;
        const float* xb  = x  + ((size_t)b * C_ + ct * 64) * N_ + nt * 64;
        u16*         xTb = xT + ((size_t)b * N_ + nt * 64) * C_ + ct * 64;
        {
            const int p  = t >> 3;
            const int n8 = t & 7;
            const float* r0 = xb + (size_t)(2 * p)     * N_ + n8 * 8;
            const float* r1 = xb + (size_t)(2 * p + 1) * N_ + n8 * 8;
            const float4 a0 = *(const float4*)(r0);
            const float4 a1 = *(const float4*)(r0 + 4);
            const float4 c0 = *(const float4*)(r1);
            const float4 c1 = *(const float4*)(r1 + 4);
            const float av[8] = { a0.x, a0.y, a0.z, a0.w, a1.x, a1.y, a1.z, a1.w };
            const float cv[8] = { c0.x, c0.y, c0.z, c0.w, c1.x, c1.y, c1.z, c1.w };
            #pragma unroll
            for (int j = 0; j < 8; j++)
                tile[n8 * 8 + j][p] = (u32)f2bf(av[j]) | ((u32)f2bf(cv[j]) << 16);
        }
        __syncthreads();
        #pragma unroll
        for (int h = 0; h < 2; h++) {
            const int id = t + h * 256;
            const int n  = id >> 3;
            const int q  = id & 7;
            uint4 val;
            val.x = tile[n][q * 4 + 0];
            val.y = tile[n][q * 4 + 1];
            val.z = tile[n][q * 4 + 2];
            val.w = tile[n][q * 4 + 3];
            *(uint4*)(xTb + (size_t)n * C_ + q * 8) = val;
        }
        __syncthreads();              // tile reuse across it-loop
    }
}

// ---------------------------------------------------------------------------
// GENERAL PATH (device-gated on gamma != 0; exact no-op when gamma == 0).
// ---------------------------------------------------------------------------
__global__ __launch_bounds__(256) void proj_kernel(
    const u16* __restrict__ xT,
    const float* __restrict__ Wq, const float* __restrict__ bq,
    const float* __restrict__ Wk, const float* __restrict__ bk,
    const float* __restrict__ Wv, const float* __restrict__ bv,
    const float* __restrict__ gamma,
    u16* __restrict__ q, u16* __restrict__ k, u16* __restrict__ v)
{
    if (gamma[0] == 0.0f) return;
    for (int it = 0; it < 2; it++) {
        const int bid = it * 256 + blockIdx.x;
        const int b = bid >> 6;
        const int p = (bid & 63) * 64 + (threadIdx.x & 63);
        const int dg = threadIdx.x >> 6;
        const u16* xrow = xT + ((size_t)b * N_ + p) * C_;
        for (int d0 = dg * 160; d0 < dg * 160 + 160; d0++) {
            const float* wrow; float bias; u16* dst; int dd; int dim;
            if (d0 < 64)       { dd = d0;       wrow = Wq + (size_t)dd * C_; bias = bq[dd]; dst = q; dim = KD_; }
            else if (d0 < 128) { dd = d0 - 64;  wrow = Wk + (size_t)dd * C_; bias = bk[dd]; dst = k; dim = KD_; }
            else               { dd = d0 - 128; wrow = Wv + (size_t)dd * C_; bias = bv[dd]; dst = v; dim = VD_; }
            float s = bias;
            for (int c = 0; c < C_; c++) s += bf2f(xrow[c]) * wrow[c];
            dst[((size_t)b * dim + dd) * N_ + p] = f2bf(s);
        }
    }
}

__global__ __launch_bounds__(256) void attn_kernel(
    const u16* __restrict__ xT, const u16* __restrict__ q,
    const u16* __restrict__ k, const u16* __restrict__ v,
    const float* __restrict__ gamma, u16* __restrict__ yT)
{
    const float g = gamma[0];
    if (g == 0.0f) return;
    __shared__ float pls[4][64];
    const int wv = threadIdx.x >> 6, lane = threadIdx.x & 63;
    for (int it = 0; it < 4; it++) {
        const int bid = it * 256 + blockIdx.x;
        const int b  = bid >> 7;
        const int q0 = (bid & 127) * 32 + wv * 8;
        const u16* kb = k + (size_t)b * KD_ * N_;
        const u16* vb = v + (size_t)b * VD_ * N_;
        for (int qi = 0; qi < 8; qi++) {
            const int i = q0 + qi;
            const float qv = bf2f(q[((size_t)b * KD_ + lane) * N_ + i]);
            float mx = -1e30f, l = 0.f;
            for (int jb = 0; jb < N_; jb += 64) {
                float e = 0.f;
                for (int kd = 0; kd < 64; kd++)
                    e += __shfl(qv, kd) * bf2f(kb[(size_t)kd * N_ + jb + lane]);
                const float nm = fmaxf(mx, e);
                l = l * __expf(mx - nm) + __expf(e - nm);
                mx = nm;
            }
            for (int off = 32; off; off >>= 1) {
                const float mo = __shfl_xor(mx, off);
                const float lo = __shfl_xor(l, off);
                const float nm = fmaxf(mx, mo);
                l = l * __expf(mx - nm) + lo * __expf(mo - nm);
                mx = nm;
            }
            float oacc[8];
            #pragma unroll
            for (int r = 0; r < 8; r++) oacc[r] = 0.f;
            for (int jb = 0; jb < N_; jb += 64) {
                float e = 0.f;
                for (int kd = 0; kd < 64; kd++)
                    e += __shfl(qv, kd) * bf2f(kb[(size_t)kd * N_ + jb + lane]);
                __syncthreads();
                pls[wv][lane] = __expf(e - mx);
                __syncthreads();
                for (int jj = 0; jj < 64; jj++) {
                    const float p = pls[wv][jj];
                    #pragma unroll
                    for (int r = 0; r < 8; r++)
                        oacc[r] += p * bf2f(vb[(size_t)(r * 64 + lane) * N_ + jb + jj]);
                }
            }
            const float inv = 1.f / l;
            #pragma unroll
            for (int r = 0; r < 8; r++) {
                const size_t idx = ((size_t)b * N_ + i) * C_ + r * 64 + lane;
                yT[idx] = f2bf(g * oacc[r] * inv + bf2f(xT[idx]));
            }
        }
    }
}

// ---------------------------------------------------------------------------
// Fused GEMM: Out[b][o][n] = ReLU(BN(sum_c Wf[o][c] * A[b][n][c])),
// A = xT (gamma==0) or yT (gamma!=0), bf16 pixel-major [B][N][C].
// Round-9: r8's m97-faithful structure (gemm 52 -> ~34us), ONE change:
// __launch_bounds__(256,3) -> (256,4). r8's kernel has no VGPR prefetch
// state (~40 arch + 64 acc + 32 transient frags ~ 110 regs), so it fits the
// 128-reg budget of 4 waves/EU — unlike r3's prefetch-laden 150. Grid 1024
// = exactly one generation at 4 blocks/CU; the 4th out-of-phase resident
// block covers each step's vmcnt(0)+barrier drain.
// Spill tripwire (r3 lesson): gemm WRITE_SIZE must stay ~66 MB; gemm
// re-appearing in top-5 above the 40us fills = regression signal.
// ---------------------------------------------------------------------------
__global__ __launch_bounds__(256, 4) void gemm_bn_relu(
    const u16* __restrict__ xT, const u16* __restrict__ yT,
    const u16* __restrict__ Wf16, const float* __restrict__ gamma,
    const float* __restrict__ bnw, const float* __restrict__ bnb,
    const float* __restrict__ bnm, const float* __restrict__ bnv,
    float* __restrict__ out)
{
    __shared__ u16 lds_a[128 * 32];
    __shared__ u16 lds_b[128 * 32];

    // bijective XCD swizzle (1024 % 8 == 0), then ot-minor decode
    const int wg = (blockIdx.x & 7) * 128 + (blockIdx.x >> 3);
    const int ot = wg & 3;
    const int mt = wg >> 2;                // 256 pixel-tiles
    const int b  = mt >> 5;
    const int px0 = (mt & 31) * 128;

    const int t = threadIdx.x;
    const int lane = t & 63;
    const int wv = t >> 6;
    const int wm = wv >> 1;
    const int wn = wv & 1;
    const int lcol = lane & 15;
    const int kq = lane >> 4;

    // staging decode: LDS slot s -> (row = s>>2, chunk-pos = s&3);
    // instr0 covers slots 0..255 (rows 0..63), instr1 slots 256..511.
    const int rs = t >> 2, ps = t & 3;
    const int ql = (ps - swz(rs)) & 3;     // logical chunk this slot holds
    const u16* Asrc = (gamma[0] == 0.0f) ? xT : yT;
    const u16* ga0 = Asrc + ((size_t)(b * N_ + px0 + rs)) * C_ + ql * 8;
    const u16* ga1 = ga0 + (size_t)64 * C_;
    const u16* gb0 = Wf16 + ((size_t)(ot * 128 + rs)) * C_ + ql * 8;
    const u16* gb1 = gb0 + (size_t)64 * C_;
    u16* la0 = lds_a + wv * 512;           // wave-uniform LDS bases
    u16* la1 = lds_a + 2048 + wv * 512;
    u16* lb0 = lds_b + wv * 512;
    u16* lb1 = lds_b + 2048 + wv * 512;

    // frag read addresses (u16 units), forward-rotated chunk
    int aaddr[4], baddr[4];
    #pragma unroll
    for (int i = 0; i < 4; i++) {
        const int P = wm * 64 + i * 16 + lcol;
        aaddr[i] = P * 32 + ((kq + swz(P)) & 3) * 8;
        const int R = wn * 64 + i * 16 + lcol;
        baddr[i] = R * 32 + ((kq + swz(R)) & 3) * 8;
    }

    f32x4 acc[4][4];
    #pragma unroll
    for (int i = 0; i < 4; i++)
        #pragma unroll
        for (int j = 0; j < 4; j++)
            acc[i][j] = (f32x4){0.f, 0.f, 0.f, 0.f};

    #pragma unroll
    for (int ks = 0; ks < 16; ++ks) {
        gld16(ga0 + ks * 32, la0);
        gld16(ga1 + ks * 32, la1);
        gld16(gb0 + ks * 32, lb0);
        gld16(gb1 + ks * 32, lb1);
        __syncthreads();               // vmcnt(0) drain: tiles landed
        bf16x8 af[4], bfg[4];
        #pragma unroll
        for (int mi = 0; mi < 4; mi++)
            af[mi] = *(const bf16x8*)&lds_a[aaddr[mi]];
        #pragma unroll
        for (int ni = 0; ni < 4; ni++)
            bfg[ni] = *(const bf16x8*)&lds_b[baddr[ni]];
        #pragma unroll
        for (int mi = 0; mi < 4; mi++)
            #pragma unroll
            for (int ni = 0; ni < 4; ni++)
                acc[mi][ni] = __builtin_amdgcn_mfma_f32_16x16x32_bf16(
                    af[mi], bfg[ni], acc[mi][ni], 0, 0, 0);
        __syncthreads();               // all reads done before next overwrite
    }

    float scale[4], shift[4];
    #pragma unroll
    for (int ni = 0; ni < 4; ni++) {
        const int o = ot * 128 + wn * 64 + ni * 16 + lcol;
        const float s = bnw[o] * rsqrtf(bnv[o] + 1e-5f);
        scale[ni] = s;
        shift[ni] = bnb[o] - bnm[o] * s;
    }
    #pragma unroll
    for (int mi = 0; mi < 4; mi++) {
        const int npix = px0 + wm * 64 + mi * 16 + kq * 4;
        #pragma unroll
        for (int ni = 0; ni < 4; ni++) {
            const int o = ot * 128 + wn * 64 + ni * 16 + lcol;
            f32x4 pk;
            #pragma unroll
            for (int r = 0; r < 4; r++)
                pk[r] = fmaxf(acc[mi][ni][r] * scale[ni] + shift[ni], 0.0f);
            *(f32x4*)(out + ((size_t)b * OD_ + o) * N_ + npix) = pk;
        }
    }
}

extern "C" void kernel_launch(void* const* d_in, const int* in_sizes, int n_in,
                              void* d_out, int out_size, void* d_ws, size_t ws_size,
                              hipStream_t stream) {
    const float* x     = (const float*)d_in[0];
    const float* Wq    = (const float*)d_in[1];
    const float* bq    = (const float*)d_in[2];
    const float* Wk    = (const float*)d_in[3];
    const float* bk    = (const float*)d_in[4];
    const float* Wv    = (const float*)d_in[5];
    const float* bv    = (const float*)d_in[6];
    const float* gamma = (const float*)d_in[7];
    const float* Wf    = (const float*)d_in[8];
    const float* bnw   = (const float*)d_in[9];
    const float* bnb   = (const float*)d_in[10];
    const float* bnm   = (const float*)d_in[11];
    const float* bnv   = (const float*)d_in[12];
    float* out = (float*)d_out;

    char* ws = (char*)d_ws;
    u16* Wf16 = (u16*)(ws);                  //     524,288 B (always)
    u16* xT   = (u16*)(ws + 524288);         // 33,554,432 B (always: gemm A-source)
    u16* yT   = (u16*)(ws + 34078720);       // 33,554,432 B (gated)
    u16* q    = (u16*)(ws + 67633152);       //  4,194,304 B (gated)
    u16* k    = (u16*)(ws + 71827456);       //  4,194,304 B (gated)
    u16* v    = (u16*)(ws + 76021760);       // 33,554,432 B (gated)

    transpose_convert_kernel<<<1040, 256, 0, stream>>>(x, Wf, xT, Wf16);
    proj_kernel<<<256, 256, 0, stream>>>(xT, Wq, bq, Wk, bk, Wv, bv, gamma, q, k, v);
    attn_kernel<<<256, 256, 0, stream>>>(xT, q, k, v, gamma, yT);
    gemm_bn_relu<<<1024, 256, 0, stream>>>(xT, yT, Wf16, gamma, bnw, bnb, bnm, bnv, out);
}